// Round 1
// baseline (565.927 us; speedup 1.0000x reference)
//
#include <hip/hip_runtime.h>
#include <hip/hip_bf16.h>

#define NX 8192
#define NN 8192
#define DIN 512
#define DHID 32
#define DOUT 256

typedef __bf16 bf16x8 __attribute__((ext_vector_type(8)));
typedef float f32x4 __attribute__((ext_vector_type(4)));
typedef unsigned short u16x8 __attribute__((ext_vector_type(8)));

__device__ __forceinline__ unsigned short f2bf(float f) {
  __hip_bfloat16 h = __float2bfloat16(f);
  return __builtin_bit_cast(unsigned short, h);
}
__device__ __forceinline__ float bf2f(unsigned short u) {
  unsigned int v = ((unsigned int)u) << 16;
  return __builtin_bit_cast(float, v);
}
__device__ __forceinline__ f32x4 mfma16(u16x8 a, u16x8 b, f32x4 c) {
  return __builtin_amdgcn_mfma_f32_16x16x32_bf16(
      __builtin_bit_cast(bf16x8, a), __builtin_bit_cast(bf16x8, b), c, 0, 0, 0);
}
__device__ __forceinline__ u16x8 cvt8(float4 a0, float4 a1) {
  u16x8 u;
  u[0] = f2bf(a0.x); u[1] = f2bf(a0.y); u[2] = f2bf(a0.z); u[3] = f2bf(a0.w);
  u[4] = f2bf(a1.x); u[5] = f2bf(a1.y); u[6] = f2bf(a1.z); u[7] = f2bf(a1.w);
  return u;
}

// ---------------- K0: transpose + bf16-convert all weight matrices ----------
__global__ __launch_bounds__(256) void k_wt(
    const float* __restrict__ Wv, const float* __restrict__ Wfx,
    const float* __restrict__ Wx1, const float* __restrict__ Wn1,
    const float* __restrict__ Wx2, const float* __restrict__ Wn2,
    unsigned short* __restrict__ WvT, unsigned short* __restrict__ WfxT,
    unsigned short* __restrict__ Wx1T, unsigned short* __restrict__ Wn1T,
    unsigned short* __restrict__ Wx2T, unsigned short* __restrict__ Wn2T) {
  const float* src; unsigned short* dst; int C, n;
  switch (blockIdx.y) {
    case 0:  src = Wv;  dst = WvT;  C = 256; n = DIN * 256; break;
    case 1:  src = Wfx; dst = WfxT; C = 256; n = DIN * 256; break;
    case 2:  src = Wx1; dst = Wx1T; C = 32;  n = DIN * 32;  break;
    case 3:  src = Wn1; dst = Wn1T; C = 32;  n = DIN * 32;  break;
    case 4:  src = Wx2; dst = Wx2T; C = 32;  n = 32 * 32;   break;
    default: src = Wn2; dst = Wn2T; C = 32;  n = 32 * 32;   break;
  }
  int idx = blockIdx.x * 256 + threadIdx.x;
  if (idx >= n) return;
  int K = n / C;
  int k = idx / C, c = idx % C;
  dst[c * K + k] = f2bf(src[idx]);
}

// ---------------- K1a: H = tanh(A @ W1 + b1), bf16 out --------------------
__global__ __launch_bounds__(256) void k_hidden(
    const float* __restrict__ x, const float* __restrict__ neigh,
    const float* __restrict__ bx1, const float* __restrict__ bn1,
    const unsigned short* __restrict__ Wx1T, const unsigned short* __restrict__ Wn1T,
    unsigned short* __restrict__ Hx, unsigned short* __restrict__ Hn) {
  const float* A; const float* b1; const unsigned short* WT; unsigned short* H;
  if (blockIdx.y == 0) { A = x; b1 = bx1; WT = Wx1T; H = Hx; }
  else                 { A = neigh; b1 = bn1; WT = Wn1T; H = Hn; }
  int lane = threadIdx.x & 63, w = threadIdx.x >> 6;
  int r = lane & 15, h4 = lane >> 4;
  int row = blockIdx.x * 64 + w * 16 + r;
  const float* ap = A + (long)row * DIN;
  f32x4 acc0 = {0.f, 0.f, 0.f, 0.f}, acc1 = {0.f, 0.f, 0.f, 0.f};
  for (int kk = 0; kk < 16; ++kk) {
    int k0 = kk * 32 + h4 * 8;
    float4 a0 = *reinterpret_cast<const float4*>(ap + k0);
    float4 a1 = *reinterpret_cast<const float4*>(ap + k0 + 4);
    u16x8 af = cvt8(a0, a1);
    u16x8 bf0 = *reinterpret_cast<const u16x8*>(WT + r * DIN + k0);
    u16x8 bf1 = *reinterpret_cast<const u16x8*>(WT + (16 + r) * DIN + k0);
    acc0 = mfma16(af, bf0, acc0);
    acc1 = mfma16(af, bf1, acc1);
  }
  int orow = blockIdx.x * 64 + w * 16 + h4 * 4;
  #pragma unroll
  for (int j = 0; j < 4; ++j) {
    H[(orow + j) * DHID + r]      = f2bf(tanhf(acc0[j] + b1[r]));
    H[(orow + j) * DHID + 16 + r] = f2bf(tanhf(acc1[j] + b1[16 + r]));
  }
}

// ---------------- K1b: att = H @ W2 + b2, bf16 out ------------------------
__global__ __launch_bounds__(256) void k_att(
    const unsigned short* __restrict__ Hx, const unsigned short* __restrict__ Hn,
    const float* __restrict__ bx2, const float* __restrict__ bn2,
    const unsigned short* __restrict__ Wx2T, const unsigned short* __restrict__ Wn2T,
    unsigned short* __restrict__ xatt, unsigned short* __restrict__ natt) {
  const unsigned short* H; const float* b2; const unsigned short* WT; unsigned short* att;
  if (blockIdx.y == 0) { H = Hx; b2 = bx2; WT = Wx2T; att = xatt; }
  else                 { H = Hn; b2 = bn2; WT = Wn2T; att = natt; }
  int lane = threadIdx.x & 63, w = threadIdx.x >> 6;
  int r = lane & 15, h4 = lane >> 4;
  int row = blockIdx.x * 64 + w * 16 + r;
  u16x8 af = *reinterpret_cast<const u16x8*>(H + row * DHID + h4 * 8);
  u16x8 b0 = *reinterpret_cast<const u16x8*>(WT + r * DHID + h4 * 8);
  u16x8 b1 = *reinterpret_cast<const u16x8*>(WT + (16 + r) * DHID + h4 * 8);
  f32x4 z = {0.f, 0.f, 0.f, 0.f};
  f32x4 acc0 = mfma16(af, b0, z);
  f32x4 acc1 = mfma16(af, b1, z);
  int orow = blockIdx.x * 64 + w * 16 + h4 * 4;
  #pragma unroll
  for (int j = 0; j < 4; ++j) {
    att[(orow + j) * DHID + r]      = f2bf(acc0[j] + b2[r]);
    att[(orow + j) * DHID + 16 + r] = f2bf(acc1[j] + b2[16 + r]);
  }
}

// ---------------- K2: fc_x -> out left half; value -> Vp (K-packed bf16) --
__global__ __launch_bounds__(256) void k_vfc(
    const float* __restrict__ x, const float* __restrict__ neigh,
    const float* __restrict__ bfx, const float* __restrict__ bv,
    const unsigned short* __restrict__ WfxT, const unsigned short* __restrict__ WvT,
    float* __restrict__ out, unsigned short* __restrict__ Vp) {
  int job = blockIdx.y;
  const float* A = job ? neigh : x;
  const float* bias = job ? bv : bfx;
  const unsigned short* WT = job ? WvT : WfxT;
  __shared__ __align__(16) char As[64 * 64];  // 64 rows x 32 bf16, XOR-swizzled
  int t = threadIdx.x;
  int lane = t & 63, w = t >> 6;
  int r = lane & 15, h4 = lane >> 4;
  int bm = blockIdx.x * 64;
  f32x4 acc[4][4];
  #pragma unroll
  for (int i = 0; i < 4; ++i)
    #pragma unroll
    for (int j = 0; j < 4; ++j) acc[i][j] = (f32x4){0.f, 0.f, 0.f, 0.f};
  int srow = t >> 2, kq = t & 3;
  const float* ap = A + (long)(bm + srow) * DIN + kq * 8;
  for (int kk = 0; kk < 16; ++kk) {
    float4 a0 = *reinterpret_cast<const float4*>(ap + kk * 32);
    float4 a1 = *reinterpret_cast<const float4*>(ap + kk * 32 + 4);
    u16x8 u = cvt8(a0, a1);
    int boff = (srow * 64 + kq * 16) ^ ((srow & 3) << 4);
    *reinterpret_cast<u16x8*>(As + boff) = u;
    __syncthreads();
    u16x8 pb[4];
    #pragma unroll
    for (int nt = 0; nt < 4; ++nt)
      pb[nt] = *reinterpret_cast<const u16x8*>(WT + (w * 64 + nt * 16 + r) * DIN + kk * 32 + h4 * 8);
    #pragma unroll
    for (int mt = 0; mt < 4; ++mt) {
      int ro = mt * 16 + r;
      int aoff = (ro * 64 + h4 * 16) ^ ((ro & 3) << 4);
      u16x8 pa = *reinterpret_cast<const u16x8*>(As + aoff);
      #pragma unroll
      for (int nt = 0; nt < 4; ++nt) acc[mt][nt] = mfma16(pa, pb[nt], acc[mt][nt]);
    }
    __syncthreads();
  }
  #pragma unroll
  for (int mt = 0; mt < 4; ++mt)
    #pragma unroll
    for (int nt = 0; nt < 4; ++nt) {
      int c = w * 64 + nt * 16 + r;
      #pragma unroll
      for (int j = 0; j < 4; ++j) {
        int row = bm + mt * 16 + h4 * 4 + j;
        float v = acc[mt][nt][j] + bias[c];
        if (job == 0) out[(long)row * 512 + c] = v;
        else Vp[((row >> 3) * 256 + c) * 8 + (row & 7)] = f2bf(v);
      }
    }
}

// ---------------- K3: fused flash attention over neighbors ----------------
__global__ __launch_bounds__(256) void k_flash(
    const int* __restrict__ adj, const unsigned short* __restrict__ xatt,
    const unsigned short* __restrict__ natt, const unsigned short* __restrict__ Vp,
    float* __restrict__ out, float* __restrict__ accP, float* __restrict__ lP, int nc) {
  __shared__ unsigned short P[32 * 72];  // 32 rows x 64 cols, pad to 72 (144 B rows)
  __shared__ float lsum[32];
  int t = threadIdx.x;
  if (t < 32) lsum[t] = 0.f;
  int lane = t & 63, w = t >> 6;
  int r = lane & 15, h4 = lane >> 4;
  int rb = blockIdx.x * 32;
  int L = NN / nc;
  int base = blockIdx.y * L;
  int NIT = L / 64;
  u16x8 qf0 = *reinterpret_cast<const u16x8*>(xatt + (rb + r) * DHID + h4 * 8);
  u16x8 qf1 = *reinterpret_cast<const u16x8*>(xatt + (rb + 16 + r) * DHID + h4 * 8);
  f32x4 o[2][4];
  #pragma unroll
  for (int i = 0; i < 2; ++i)
    #pragma unroll
    for (int j = 0; j < 4; ++j) o[i][j] = (f32x4){0.f, 0.f, 0.f, 0.f};
  int acur[8];
  #pragma unroll
  for (int rt = 0; rt < 2; ++rt)
    #pragma unroll
    for (int j = 0; j < 4; ++j)
      acur[rt * 4 + j] = adj[(long)(rb + rt * 16 + h4 * 4 + j) * NN + base + w * 16 + r];
  __syncthreads();
  for (int it = 0; it < NIT; ++it) {
    int n0 = base + it * 64;
    u16x8 kf = *reinterpret_cast<const u16x8*>(natt + (n0 + w * 16 + r) * DHID + h4 * 8);
    f32x4 z = {0.f, 0.f, 0.f, 0.f};
    f32x4 s0 = mfma16(qf0, kf, z);
    f32x4 s1 = mfma16(qf1, kf, z);
    int anext[8];
    int nn0 = (it + 1 < NIT) ? (n0 + 64) : n0;  // software prefetch (clamped)
    #pragma unroll
    for (int rt = 0; rt < 2; ++rt)
      #pragma unroll
      for (int j = 0; j < 4; ++j)
        anext[rt * 4 + j] = adj[(long)(rb + rt * 16 + h4 * 4 + j) * NN + nn0 + w * 16 + r];
    #pragma unroll
    for (int rt = 0; rt < 2; ++rt) {
      f32x4 s = rt ? s1 : s0;
      #pragma unroll
      for (int j = 0; j < 4; ++j) {
        float sv = s[j];
        float lr = fminf(fmaxf(sv, 0.01f * sv), 60.f);  // leaky_relu + overflow guard
        float p = (acur[rt * 4 + j] > 0) ? __expf(lr) : 0.f;
        P[(rt * 16 + h4 * 4 + j) * 72 + w * 16 + r] = f2bf(p);
      }
    }
    #pragma unroll
    for (int q = 0; q < 8; ++q) acur[q] = anext[q];
    __syncthreads();
    {  // denominator partials from the same bf16 P that feeds PV
      int trow = t >> 3, tq = t & 7;
      u16x8 pv = *reinterpret_cast<const u16x8*>(P + trow * 72 + tq * 8);
      float s8 = 0.f;
      #pragma unroll
      for (int i = 0; i < 8; ++i) s8 += bf2f(pv[i]);
      s8 += __shfl_xor(s8, 1);
      s8 += __shfl_xor(s8, 2);
      s8 += __shfl_xor(s8, 4);
      if (tq == 0) lsum[trow] += s8;
    }
    #pragma unroll
    for (int kb = 0; kb < 2; ++kb) {
      u16x8 pa0 = *reinterpret_cast<const u16x8*>(P + r * 72 + kb * 32 + h4 * 8);
      u16x8 pa1 = *reinterpret_cast<const u16x8*>(P + (16 + r) * 72 + kb * 32 + h4 * 8);
      long vbase = ((long)((n0 + kb * 32) >> 3) + h4) * (DOUT * 8);
      #pragma unroll
      for (int nt = 0; nt < 4; ++nt) {
        u16x8 vf = *reinterpret_cast<const u16x8*>(Vp + vbase + (w * 64 + nt * 16 + r) * 8);
        o[0][nt] = mfma16(pa0, vf, o[0][nt]);
        o[1][nt] = mfma16(pa1, vf, o[1][nt]);
      }
    }
    __syncthreads();
  }
  if (nc == 1) {
    #pragma unroll
    for (int rt = 0; rt < 2; ++rt)
      #pragma unroll
      for (int nt = 0; nt < 4; ++nt) {
        int c = w * 64 + nt * 16 + r;
        #pragma unroll
        for (int j = 0; j < 4; ++j) {
          int rl = rt * 16 + h4 * 4 + j;
          out[(long)(rb + rl) * 512 + 256 + c] = o[rt][nt][j] / lsum[rl];
        }
      }
  } else {
    long cb = (long)blockIdx.y * NX;
    #pragma unroll
    for (int rt = 0; rt < 2; ++rt)
      #pragma unroll
      for (int nt = 0; nt < 4; ++nt) {
        int c = w * 64 + nt * 16 + r;
        #pragma unroll
        for (int j = 0; j < 4; ++j) {
          int rl = rt * 16 + h4 * 4 + j;
          accP[(cb + rb + rl) * DOUT + c] = o[rt][nt][j];
        }
      }
    if (t < 32) lP[blockIdx.y * NX + rb + t] = lsum[t];
  }
}

// ---------------- K4: combine neighbor-chunk partials ---------------------
__global__ __launch_bounds__(256) void k_combine(
    const float* __restrict__ accP, const float* __restrict__ lP,
    float* __restrict__ out, int nc) {
  long idx = (long)blockIdx.x * 256 + threadIdx.x;  // over NX*DOUT
  int row = (int)(idx >> 8), c = (int)(idx & 255);
  float s = 0.f, l = 0.f;
  for (int q = 0; q < nc; ++q) {
    s += accP[(long)q * NX * DOUT + idx];
    l += lP[q * NX + row];
  }
  out[(long)row * 512 + 256 + c] = s / l;
}

extern "C" void kernel_launch(void* const* d_in, const int* in_sizes, int n_in,
                              void* d_out, int out_size, void* d_ws, size_t ws_size,
                              hipStream_t stream) {
  const float* x    = (const float*)d_in[0];
  const float* neigh= (const float*)d_in[1];
  const int*   adj  = (const int*)d_in[2];
  const float* Wx1  = (const float*)d_in[3];
  const float* bx1  = (const float*)d_in[4];
  const float* Wx2  = (const float*)d_in[5];
  const float* bx2  = (const float*)d_in[6];
  const float* Wn1  = (const float*)d_in[7];
  const float* bn1  = (const float*)d_in[8];
  const float* Wn2  = (const float*)d_in[9];
  const float* bn2  = (const float*)d_in[10];
  const float* Wv   = (const float*)d_in[11];
  const float* bv   = (const float*)d_in[12];
  const float* Wfx  = (const float*)d_in[13];
  const float* bfx  = (const float*)d_in[14];
  float* out = (float*)d_out;
  char* ws = (char*)d_ws;

  unsigned short* xatt = (unsigned short*)(ws + 0);
  unsigned short* natt = (unsigned short*)(ws + 524288);
  unsigned short* Hx   = (unsigned short*)(ws + 1048576);
  unsigned short* Hn   = (unsigned short*)(ws + 1572864);
  unsigned short* Vp   = (unsigned short*)(ws + 2097152);
  unsigned short* WvT  = (unsigned short*)(ws + 6291456);
  unsigned short* WfxT = (unsigned short*)(ws + 6553600);
  unsigned short* Wx1T = (unsigned short*)(ws + 6815744);
  unsigned short* Wn1T = (unsigned short*)(ws + 6848512);
  unsigned short* Wx2T = (unsigned short*)(ws + 6881280);
  unsigned short* Wn2T = (unsigned short*)(ws + 6883328);

  const size_t OFF_ACC = 8388608;
  const size_t CHUNK_ACC = (size_t)NX * DOUT * 4;  // 8 MB per chunk
  size_t need4 = OFF_ACC + 4 * CHUNK_ACC + 4 * NX * 4;
  size_t need2 = OFF_ACC + 2 * CHUNK_ACC + 2 * NX * 4;
  int nc = (ws_size >= need4) ? 4 : (ws_size >= need2) ? 2 : 1;
  float* accP = (float*)(ws + OFF_ACC);
  float* lP   = (float*)(ws + OFF_ACC + (size_t)nc * CHUNK_ACC);

  k_wt<<<dim3(512, 6), 256, 0, stream>>>(Wv, Wfx, Wx1, Wn1, Wx2, Wn2,
                                         WvT, WfxT, Wx1T, Wn1T, Wx2T, Wn2T);
  k_hidden<<<dim3(128, 2), 256, 0, stream>>>(x, neigh, bx1, bn1, Wx1T, Wn1T, Hx, Hn);
  k_att<<<dim3(128, 2), 256, 0, stream>>>(Hx, Hn, bx2, bn2, Wx2T, Wn2T, xatt, natt);
  k_vfc<<<dim3(128, 2), 256, 0, stream>>>(x, neigh, bfx, bv, WfxT, WvT, out, Vp);
  k_flash<<<dim3(256, nc), 256, 0, stream>>>(adj, xatt, natt, Vp, out, accP, lP, nc);
  if (nc > 1)
    k_combine<<<dim3(NX * DOUT / 256), 256, 0, stream>>>(accP, lP, out, nc);
}

// Round 3
// 520.875 us; speedup vs baseline: 1.0865x; 1.0865x over previous
//
#include <hip/hip_runtime.h>
#include <hip/hip_bf16.h>

#define NX 8192
#define NN 8192
#define DIN 512
#define DHID 32
#define DOUT 256

typedef __bf16 bf16x8 __attribute__((ext_vector_type(8)));
typedef float f32x4 __attribute__((ext_vector_type(4)));
typedef unsigned short u16x8 __attribute__((ext_vector_type(8)));

__device__ __forceinline__ unsigned short f2bf(float f) {
  __hip_bfloat16 h = __float2bfloat16(f);
  return __builtin_bit_cast(unsigned short, h);
}
__device__ __forceinline__ float bf2f(unsigned short u) {
  unsigned int v = ((unsigned int)u) << 16;
  return __builtin_bit_cast(float, v);
}
__device__ __forceinline__ f32x4 mfma16(u16x8 a, u16x8 b, f32x4 c) {
  return __builtin_amdgcn_mfma_f32_16x16x32_bf16(
      __builtin_bit_cast(bf16x8, a), __builtin_bit_cast(bf16x8, b), c, 0, 0, 0);
}
__device__ __forceinline__ u16x8 cvt8(float4 a0, float4 a1) {
  u16x8 u;
  u[0] = f2bf(a0.x); u[1] = f2bf(a0.y); u[2] = f2bf(a0.z); u[3] = f2bf(a0.w);
  u[4] = f2bf(a1.x); u[5] = f2bf(a1.y); u[6] = f2bf(a1.z); u[7] = f2bf(a1.w);
  return u;
}

// ---------------- K0: LDS-tiled transpose + bf16 convert ------------------
__global__ __launch_bounds__(256) void k_wt(
    const float* __restrict__ Wv, const float* __restrict__ Wfx,
    const float* __restrict__ Wx1, const float* __restrict__ Wn1,
    const float* __restrict__ Wx2, const float* __restrict__ Wn2,
    unsigned short* __restrict__ WvT, unsigned short* __restrict__ WfxT,
    unsigned short* __restrict__ Wx1T, unsigned short* __restrict__ Wn1T,
    unsigned short* __restrict__ Wx2T, unsigned short* __restrict__ Wn2T) {
  const float* src; unsigned short* dst; int K, C;
  switch (blockIdx.y) {
    case 0:  src = Wv;  dst = WvT;  K = DIN; C = 256; break;
    case 1:  src = Wfx; dst = WfxT; K = DIN; C = 256; break;
    case 2:  src = Wx1; dst = Wx1T; K = DIN; C = 32;  break;
    case 3:  src = Wn1; dst = Wn1T; K = DIN; C = 32;  break;
    case 4:  src = Wx2; dst = Wx2T; K = 32;  C = 32;  break;
    default: src = Wn2; dst = Wn2T; K = 32;  C = 32;  break;
  }
  int tc = C >> 5, tk = K >> 5;
  if ((int)blockIdx.x >= tc * tk) return;
  int ik = blockIdx.x / tc, ic = blockIdx.x % tc;
  __shared__ float tile[32][33];
  int t = threadIdx.x, tx = t & 31, ty0 = t >> 5;
  #pragma unroll
  for (int q = 0; q < 4; ++q) {
    int ty = ty0 + q * 8;
    tile[ty][tx] = src[(ik * 32 + ty) * C + ic * 32 + tx];
  }
  __syncthreads();
  #pragma unroll
  for (int q = 0; q < 4; ++q) {
    int ty = ty0 + q * 8;
    dst[(ic * 32 + ty) * K + ik * 32 + tx] = f2bf(tile[tx][ty]);
  }
}

// ------- K1: merged prep GEMM: A@{Wfx|Wv} (N=256) and tanh(A@W1) (N=32) ----
// Double-buffered LDS A-tile, ONE full __syncthreads per K-step; A/W register
// prefetch issued right after the barrier so the next barrier's vmcnt drain
// lands mostly-complete.
__global__ __launch_bounds__(256) void k_prep(
    const float* __restrict__ x, const float* __restrict__ neigh,
    const float* __restrict__ bfx, const float* __restrict__ bv,
    const float* __restrict__ bx1, const float* __restrict__ bn1,
    const unsigned short* __restrict__ WfxT, const unsigned short* __restrict__ WvT,
    const unsigned short* __restrict__ Wx1T, const unsigned short* __restrict__ Wn1T,
    float* __restrict__ out, unsigned short* __restrict__ Vp,
    unsigned short* __restrict__ Hx, unsigned short* __restrict__ Hn) {
  int job = blockIdx.y;
  const float* A = job ? neigh : x;
  const float* bias = job ? bv : bfx;
  const float* b1 = job ? bn1 : bx1;
  const unsigned short* WT = job ? WvT : WfxT;
  const unsigned short* W1T = job ? Wn1T : Wx1T;
  unsigned short* H = job ? Hn : Hx;
  __shared__ __align__(16) char As[2][64 * 64];  // 2 x (64 rows x 32 bf16), swizzled
  int t = threadIdx.x;
  int lane = t & 63, w = t >> 6;
  int r = lane & 15, h4 = lane >> 4;
  int bm = blockIdx.x * 64;
  f32x4 acc[4][4];
  f32x4 acch[4];
  #pragma unroll
  for (int i = 0; i < 4; ++i) {
    acch[i] = (f32x4){0.f, 0.f, 0.f, 0.f};
    #pragma unroll
    for (int j = 0; j < 4; ++j) acc[i][j] = (f32x4){0.f, 0.f, 0.f, 0.f};
  }
  int srow = t >> 2, kq = t & 3;
  const float* ap = A + (long)(bm + srow) * DIN + kq * 8;
  float4 a0 = *reinterpret_cast<const float4*>(ap);
  float4 a1 = *reinterpret_cast<const float4*>(ap + 4);
  u16x8 pbc[4], pbhc;
  #pragma unroll
  for (int nt = 0; nt < 4; ++nt)
    pbc[nt] = *reinterpret_cast<const u16x8*>(WT + (w * 64 + nt * 16 + r) * DIN + h4 * 8);
  if (w < 2)
    pbhc = *reinterpret_cast<const u16x8*>(W1T + (w * 16 + r) * DIN + h4 * 8);
  int boff = (srow * 64 + kq * 16) ^ ((srow & 3) << 4);
  int buf = 0;
  for (int kk = 0; kk < 16; ++kk) {
    u16x8 u = cvt8(a0, a1);
    *reinterpret_cast<u16x8*>(&As[buf][0] + boff) = u;
    __syncthreads();  // full drain: As[buf] visible; safe epoch structure
    u16x8 pbn[4], pbhn;
    if (kk < 15) {  // prefetch next slices (land by next barrier's drain)
      a0 = *reinterpret_cast<const float4*>(ap + (kk + 1) * 32);
      a1 = *reinterpret_cast<const float4*>(ap + (kk + 1) * 32 + 4);
      #pragma unroll
      for (int nt = 0; nt < 4; ++nt)
        pbn[nt] = *reinterpret_cast<const u16x8*>(
            WT + (w * 64 + nt * 16 + r) * DIN + (kk + 1) * 32 + h4 * 8);
      if (w < 2)
        pbhn = *reinterpret_cast<const u16x8*>(
            W1T + (w * 16 + r) * DIN + (kk + 1) * 32 + h4 * 8);
    }
    #pragma unroll
    for (int mt = 0; mt < 4; ++mt) {
      int ro = mt * 16 + r;
      int aoff = (ro * 64 + h4 * 16) ^ ((ro & 3) << 4);
      u16x8 pa = *reinterpret_cast<const u16x8*>(&As[buf][0] + aoff);
      #pragma unroll
      for (int nt = 0; nt < 4; ++nt) acc[mt][nt] = mfma16(pa, pbc[nt], acc[mt][nt]);
      if (w < 2) acch[mt] = mfma16(pa, pbhc, acch[mt]);
    }
    #pragma unroll
    for (int nt = 0; nt < 4; ++nt) pbc[nt] = pbn[nt];
    pbhc = pbhn;
    buf ^= 1;  // next write targets other buffer; reuse separated by a barrier
  }
  #pragma unroll
  for (int mt = 0; mt < 4; ++mt)
    #pragma unroll
    for (int nt = 0; nt < 4; ++nt) {
      int c = w * 64 + nt * 16 + r;
      #pragma unroll
      for (int j = 0; j < 4; ++j) {
        int row = bm + mt * 16 + h4 * 4 + j;
        float v = acc[mt][nt][j] + bias[c];
        if (job == 0) out[(long)row * 512 + c] = v;
        else Vp[((row >> 3) * 256 + c) * 8 + (row & 7)] = f2bf(v);
      }
    }
  if (w < 2) {
    int c = w * 16 + r;
    float bb = b1[c];
    #pragma unroll
    for (int mt = 0; mt < 4; ++mt)
      #pragma unroll
      for (int j = 0; j < 4; ++j) {
        int row = bm + mt * 16 + h4 * 4 + j;
        H[row * DHID + c] = f2bf(tanhf(acch[mt][j] + bb));
      }
  }
}

// ---------------- K2: att = H @ W2 + b2, bf16 out ------------------------
__global__ __launch_bounds__(256) void k_att(
    const unsigned short* __restrict__ Hx, const unsigned short* __restrict__ Hn,
    const float* __restrict__ bx2, const float* __restrict__ bn2,
    const unsigned short* __restrict__ Wx2T, const unsigned short* __restrict__ Wn2T,
    unsigned short* __restrict__ xatt, unsigned short* __restrict__ natt) {
  const unsigned short* H; const float* b2; const unsigned short* WT; unsigned short* att;
  if (blockIdx.y == 0) { H = Hx; b2 = bx2; WT = Wx2T; att = xatt; }
  else                 { H = Hn; b2 = bn2; WT = Wn2T; att = natt; }
  int lane = threadIdx.x & 63, w = threadIdx.x >> 6;
  int r = lane & 15, h4 = lane >> 4;
  int row = blockIdx.x * 64 + w * 16 + r;
  u16x8 af = *reinterpret_cast<const u16x8*>(H + row * DHID + h4 * 8);
  u16x8 b0 = *reinterpret_cast<const u16x8*>(WT + r * DHID + h4 * 8);
  u16x8 b1 = *reinterpret_cast<const u16x8*>(WT + (16 + r) * DHID + h4 * 8);
  f32x4 z = {0.f, 0.f, 0.f, 0.f};
  f32x4 acc0 = mfma16(af, b0, z);
  f32x4 acc1 = mfma16(af, b1, z);
  int orow = blockIdx.x * 64 + w * 16 + h4 * 4;
  #pragma unroll
  for (int j = 0; j < 4; ++j) {
    att[(orow + j) * DHID + r]      = f2bf(acc0[j] + b2[r]);
    att[(orow + j) * DHID + 16 + r] = f2bf(acc1[j] + b2[16 + r]);
  }
}

// ---------------- K3: fused flash attention over neighbors ----------------
// Double-buffered P in LDS, ONE full __syncthreads per iter; adj/kf prefetch
// issued at iter start so the barrier drain lands mostly-complete. 4 blocks/CU
// hide the residual stall.
__global__ __launch_bounds__(256, 4) void k_flash(
    const int* __restrict__ adj, const unsigned short* __restrict__ xatt,
    const unsigned short* __restrict__ natt, const unsigned short* __restrict__ Vp,
    float* __restrict__ out, unsigned short* __restrict__ accP,
    float* __restrict__ lP, int nc) {
  __shared__ unsigned short P[2][32 * 72];  // double-buffered 32x64 (+pad)
  __shared__ float lpart[4][32];
  int t = threadIdx.x;
  int lane = t & 63, w = t >> 6;
  int r = lane & 15, h4 = lane >> 4;
  int rb = blockIdx.x * 32;
  int L = NN / nc;
  int base = blockIdx.y * L;
  int NIT = L / 64;
  u16x8 qf0 = *reinterpret_cast<const u16x8*>(xatt + (rb + r) * DHID + h4 * 8);
  u16x8 qf1 = *reinterpret_cast<const u16x8*>(xatt + (rb + 16 + r) * DHID + h4 * 8);
  f32x4 o[2][4];
  #pragma unroll
  for (int i = 0; i < 2; ++i)
    #pragma unroll
    for (int j = 0; j < 4; ++j) o[i][j] = (f32x4){0.f, 0.f, 0.f, 0.f};
  float psum[8];
  #pragma unroll
  for (int i = 0; i < 8; ++i) psum[i] = 0.f;
  int acur[8];
  #pragma unroll
  for (int rt = 0; rt < 2; ++rt)
    #pragma unroll
    for (int j = 0; j < 4; ++j)
      acur[rt * 4 + j] = adj[(long)(rb + rt * 16 + h4 * 4 + j) * NN + base + w * 16 + r];
  u16x8 kfc = *reinterpret_cast<const u16x8*>(natt + (base + w * 16 + r) * DHID + h4 * 8);
  int buf = 0;
  for (int it = 0; it < NIT; ++it) {
    int n0 = base + it * 64;
    int nn0 = (it + 1 < NIT) ? (n0 + 64) : n0;  // clamped prefetch
    int anext[8];
    #pragma unroll
    for (int rt = 0; rt < 2; ++rt)
      #pragma unroll
      for (int j = 0; j < 4; ++j)
        anext[rt * 4 + j] = adj[(long)(rb + rt * 16 + h4 * 4 + j) * NN + nn0 + w * 16 + r];
    u16x8 kfn = *reinterpret_cast<const u16x8*>(natt + (nn0 + w * 16 + r) * DHID + h4 * 8);
    f32x4 z = {0.f, 0.f, 0.f, 0.f};
    f32x4 s0 = mfma16(qf0, kfc, z);
    f32x4 s1 = mfma16(qf1, kfc, z);
    unsigned short* Pb = &P[buf][0];
    #pragma unroll
    for (int rt = 0; rt < 2; ++rt) {
      f32x4 s = rt ? s1 : s0;
      #pragma unroll
      for (int j = 0; j < 4; ++j) {
        float sv = s[j];
        float lr = fminf(fmaxf(sv, 0.01f * sv), 60.f);  // leaky_relu + guard
        float p = (acur[rt * 4 + j] > 0) ? __expf(lr) : 0.f;
        psum[rt * 4 + j] += p;
        Pb[(rt * 16 + h4 * 4 + j) * 72 + w * 16 + r] = f2bf(p);
      }
    }
    __syncthreads();  // full drain; P[buf] visible to all waves
    #pragma unroll
    for (int kb = 0; kb < 2; ++kb) {
      u16x8 pa0 = *reinterpret_cast<const u16x8*>(Pb + r * 72 + kb * 32 + h4 * 8);
      u16x8 pa1 = *reinterpret_cast<const u16x8*>(Pb + (16 + r) * 72 + kb * 32 + h4 * 8);
      long vbase = ((long)((n0 + kb * 32) >> 3) + h4) * (DOUT * 8);
      #pragma unroll
      for (int nt = 0; nt < 4; ++nt) {
        u16x8 vf = *reinterpret_cast<const u16x8*>(Vp + vbase + (w * 64 + nt * 16 + r) * 8);
        o[0][nt] = mfma16(pa0, vf, o[0][nt]);
        o[1][nt] = mfma16(pa1, vf, o[1][nt]);
      }
    }
    #pragma unroll
    for (int q = 0; q < 8; ++q) acur[q] = anext[q];
    kfc = kfn;
    buf ^= 1;  // reads of old buf done before next iter's barrier
  }
  // row-sum: reduce psum over the 16 r-lanes (h4 groups independent)
  #pragma unroll
  for (int q = 1; q < 16; q <<= 1)
    #pragma unroll
    for (int i = 0; i < 8; ++i) psum[i] += __shfl_xor(psum[i], q);
  if (r == 0) {
    #pragma unroll
    for (int rt = 0; rt < 2; ++rt)
      #pragma unroll
      for (int j = 0; j < 4; ++j)
        lpart[w][rt * 16 + h4 * 4 + j] = psum[rt * 4 + j];
  }
  __syncthreads();
  if (nc == 1) {
    #pragma unroll
    for (int rt = 0; rt < 2; ++rt)
      #pragma unroll
      for (int nt = 0; nt < 4; ++nt) {
        int c = w * 64 + nt * 16 + r;
        #pragma unroll
        for (int j = 0; j < 4; ++j) {
          int rl = rt * 16 + h4 * 4 + j;
          float l = lpart[0][rl] + lpart[1][rl] + lpart[2][rl] + lpart[3][rl];
          out[(long)(rb + rl) * 512 + 256 + c] = o[rt][nt][j] / l;
        }
      }
  } else {
    long cb = (long)blockIdx.y * NX;
    #pragma unroll
    for (int rt = 0; rt < 2; ++rt)
      #pragma unroll
      for (int nt = 0; nt < 4; ++nt) {
        int c = w * 64 + nt * 16 + r;
        #pragma unroll
        for (int j = 0; j < 4; ++j) {
          int rl = rt * 16 + h4 * 4 + j;
          accP[(cb + rb + rl) * DOUT + c] = f2bf(o[rt][nt][j]);
        }
      }
    if (t < 32)
      lP[blockIdx.y * NX + rb + t] =
          lpart[0][t] + lpart[1][t] + lpart[2][t] + lpart[3][t];
  }
}

// ---------------- K4: combine neighbor-chunk partials ---------------------
__global__ __launch_bounds__(256) void k_combine(
    const unsigned short* __restrict__ accP, const float* __restrict__ lP,
    float* __restrict__ out, int nc) {
  long idx = (long)blockIdx.x * 256 + threadIdx.x;  // over NX*DOUT
  int row = (int)(idx >> 8), c = (int)(idx & 255);
  float s = 0.f, l = 0.f;
  for (int q = 0; q < nc; ++q) {
    s += bf2f(accP[(long)q * NX * DOUT + idx]);
    l += lP[q * NX + row];
  }
  out[(long)row * 512 + 256 + c] = s / l;
}

extern "C" void kernel_launch(void* const* d_in, const int* in_sizes, int n_in,
                              void* d_out, int out_size, void* d_ws, size_t ws_size,
                              hipStream_t stream) {
  const float* x    = (const float*)d_in[0];
  const float* neigh= (const float*)d_in[1];
  const int*   adj  = (const int*)d_in[2];
  const float* Wx1  = (const float*)d_in[3];
  const float* bx1  = (const float*)d_in[4];
  const float* Wx2  = (const float*)d_in[5];
  const float* bx2  = (const float*)d_in[6];
  const float* Wn1  = (const float*)d_in[7];
  const float* bn1  = (const float*)d_in[8];
  const float* Wn2  = (const float*)d_in[9];
  const float* bn2  = (const float*)d_in[10];
  const float* Wv   = (const float*)d_in[11];
  const float* bv   = (const float*)d_in[12];
  const float* Wfx  = (const float*)d_in[13];
  const float* bfx  = (const float*)d_in[14];
  float* out = (float*)d_out;
  char* ws = (char*)d_ws;

  unsigned short* xatt = (unsigned short*)(ws + 0);
  unsigned short* natt = (unsigned short*)(ws + 524288);
  unsigned short* Hx   = (unsigned short*)(ws + 1048576);
  unsigned short* Hn   = (unsigned short*)(ws + 1572864);
  unsigned short* Vp   = (unsigned short*)(ws + 2097152);
  unsigned short* WvT  = (unsigned short*)(ws + 6291456);
  unsigned short* WfxT = (unsigned short*)(ws + 6553600);
  unsigned short* Wx1T = (unsigned short*)(ws + 6815744);
  unsigned short* Wn1T = (unsigned short*)(ws + 6848512);
  unsigned short* Wx2T = (unsigned short*)(ws + 6881280);
  unsigned short* Wn2T = (unsigned short*)(ws + 6883328);

  const size_t OFF_ACC = 7340032;                   // 7 MB
  const size_t CHUNK_ACC = (size_t)NX * DOUT * 2;   // 4 MB bf16 per chunk
  size_t need4 = OFF_ACC + 4 * (CHUNK_ACC + (size_t)NX * 4);
  size_t need2 = OFF_ACC + 2 * (CHUNK_ACC + (size_t)NX * 4);
  int nc = (ws_size >= need4) ? 4 : (ws_size >= need2) ? 2 : 1;
  unsigned short* accP = (unsigned short*)(ws + OFF_ACC);
  float* lP = (float*)(ws + OFF_ACC + (size_t)nc * CHUNK_ACC);

  k_wt<<<dim3(128, 6), 256, 0, stream>>>(Wv, Wfx, Wx1, Wn1, Wx2, Wn2,
                                         WvT, WfxT, Wx1T, Wn1T, Wx2T, Wn2T);
  k_prep<<<dim3(128, 2), 256, 0, stream>>>(x, neigh, bfx, bv, bx1, bn1,
                                           WfxT, WvT, Wx1T, Wn1T, out, Vp, Hx, Hn);
  k_att<<<dim3(128, 2), 256, 0, stream>>>(Hx, Hn, bx2, bn2, Wx2T, Wn2T, xatt, natt);
  k_flash<<<dim3(256, nc), 256, 0, stream>>>(adj, xatt, natt, Vp, out, accP, lP, nc);
  if (nc > 1)
    k_combine<<<dim3(NX * DOUT / 256), 256, 0, stream>>>(accP, lP, out, nc);
}

// Round 4
// 496.830 us; speedup vs baseline: 1.1391x; 1.0484x over previous
//
#include <hip/hip_runtime.h>
#include <hip/hip_bf16.h>

#define NX 8192
#define NN 8192
#define DIN 512
#define DHID 32
#define DOUT 256

typedef __bf16 bf16x8 __attribute__((ext_vector_type(8)));
typedef float f32x4 __attribute__((ext_vector_type(4)));
typedef unsigned short u16x8 __attribute__((ext_vector_type(8)));

__device__ __forceinline__ unsigned short f2bf(float f) {
  __hip_bfloat16 h = __float2bfloat16(f);
  return __builtin_bit_cast(unsigned short, h);
}
__device__ __forceinline__ float bf2f(unsigned short u) {
  unsigned int v = ((unsigned int)u) << 16;
  return __builtin_bit_cast(float, v);
}
__device__ __forceinline__ f32x4 mfma16(u16x8 a, u16x8 b, f32x4 c) {
  return __builtin_amdgcn_mfma_f32_16x16x32_bf16(
      __builtin_bit_cast(bf16x8, a), __builtin_bit_cast(bf16x8, b), c, 0, 0, 0);
}
__device__ __forceinline__ u16x8 cvt8(float4 a0, float4 a1) {
  u16x8 u;
  u[0] = f2bf(a0.x); u[1] = f2bf(a0.y); u[2] = f2bf(a0.z); u[3] = f2bf(a0.w);
  u[4] = f2bf(a1.x); u[5] = f2bf(a1.y); u[6] = f2bf(a1.z); u[7] = f2bf(a1.w);
  return u;
}

// ---------------- K0: LDS-tiled transpose + bf16 convert ------------------
__global__ __launch_bounds__(256) void k_wt(
    const float* __restrict__ Wv, const float* __restrict__ Wfx,
    const float* __restrict__ Wx1, const float* __restrict__ Wn1,
    const float* __restrict__ Wx2, const float* __restrict__ Wn2,
    unsigned short* __restrict__ WvT, unsigned short* __restrict__ WfxT,
    unsigned short* __restrict__ Wx1T, unsigned short* __restrict__ Wn1T,
    unsigned short* __restrict__ Wx2T, unsigned short* __restrict__ Wn2T) {
  const float* src; unsigned short* dst; int K, C;
  switch (blockIdx.y) {
    case 0:  src = Wv;  dst = WvT;  K = DIN; C = 256; break;
    case 1:  src = Wfx; dst = WfxT; K = DIN; C = 256; break;
    case 2:  src = Wx1; dst = Wx1T; K = DIN; C = 32;  break;
    case 3:  src = Wn1; dst = Wn1T; K = DIN; C = 32;  break;
    case 4:  src = Wx2; dst = Wx2T; K = 32;  C = 32;  break;
    default: src = Wn2; dst = Wn2T; K = 32;  C = 32;  break;
  }
  int tc = C >> 5, tk = K >> 5;
  if ((int)blockIdx.x >= tc * tk) return;
  int ik = blockIdx.x / tc, ic = blockIdx.x % tc;
  __shared__ float tile[32][33];
  int t = threadIdx.x, tx = t & 31, ty0 = t >> 5;
  #pragma unroll
  for (int q = 0; q < 4; ++q) {
    int ty = ty0 + q * 8;
    tile[ty][tx] = src[(ik * 32 + ty) * C + ic * 32 + tx];
  }
  __syncthreads();
  #pragma unroll
  for (int q = 0; q < 4; ++q) {
    int ty = ty0 + q * 8;
    dst[(ic * 32 + ty) * K + ik * 32 + tx] = f2bf(tile[tx][ty]);
  }
}

// ------- K1: merged prep GEMM: A@{Wfx|Wv} (N=256) and tanh(A@W1) (N=32) ----
__global__ __launch_bounds__(256) void k_prep(
    const float* __restrict__ x, const float* __restrict__ neigh,
    const float* __restrict__ bfx, const float* __restrict__ bv,
    const float* __restrict__ bx1, const float* __restrict__ bn1,
    const unsigned short* __restrict__ WfxT, const unsigned short* __restrict__ WvT,
    const unsigned short* __restrict__ Wx1T, const unsigned short* __restrict__ Wn1T,
    float* __restrict__ out, unsigned short* __restrict__ Vp,
    unsigned short* __restrict__ Hx, unsigned short* __restrict__ Hn) {
  int job = blockIdx.y;
  const float* A = job ? neigh : x;
  const float* bias = job ? bv : bfx;
  const float* b1 = job ? bn1 : bx1;
  const unsigned short* WT = job ? WvT : WfxT;
  const unsigned short* W1T = job ? Wn1T : Wx1T;
  unsigned short* H = job ? Hn : Hx;
  __shared__ __align__(16) char As[2][64 * 64];
  int t = threadIdx.x;
  int lane = t & 63, w = t >> 6;
  int r = lane & 15, h4 = lane >> 4;
  int bm = blockIdx.x * 64;
  f32x4 acc[4][4];
  f32x4 acch[4];
  #pragma unroll
  for (int i = 0; i < 4; ++i) {
    acch[i] = (f32x4){0.f, 0.f, 0.f, 0.f};
    #pragma unroll
    for (int j = 0; j < 4; ++j) acc[i][j] = (f32x4){0.f, 0.f, 0.f, 0.f};
  }
  int srow = t >> 2, kq = t & 3;
  const float* ap = A + (long)(bm + srow) * DIN + kq * 8;
  float4 a0 = *reinterpret_cast<const float4*>(ap);
  float4 a1 = *reinterpret_cast<const float4*>(ap + 4);
  u16x8 pbc[4], pbhc;
  #pragma unroll
  for (int nt = 0; nt < 4; ++nt)
    pbc[nt] = *reinterpret_cast<const u16x8*>(WT + (w * 64 + nt * 16 + r) * DIN + h4 * 8);
  if (w < 2)
    pbhc = *reinterpret_cast<const u16x8*>(W1T + (w * 16 + r) * DIN + h4 * 8);
  int boff = (srow * 64 + kq * 16) ^ ((srow & 3) << 4);
  int buf = 0;
  for (int kk = 0; kk < 16; ++kk) {
    u16x8 u = cvt8(a0, a1);
    *reinterpret_cast<u16x8*>(&As[buf][0] + boff) = u;
    __syncthreads();
    u16x8 pbn[4], pbhn;
    if (kk < 15) {
      a0 = *reinterpret_cast<const float4*>(ap + (kk + 1) * 32);
      a1 = *reinterpret_cast<const float4*>(ap + (kk + 1) * 32 + 4);
      #pragma unroll
      for (int nt = 0; nt < 4; ++nt)
        pbn[nt] = *reinterpret_cast<const u16x8*>(
            WT + (w * 64 + nt * 16 + r) * DIN + (kk + 1) * 32 + h4 * 8);
      if (w < 2)
        pbhn = *reinterpret_cast<const u16x8*>(
            W1T + (w * 16 + r) * DIN + (kk + 1) * 32 + h4 * 8);
    }
    #pragma unroll
    for (int mt = 0; mt < 4; ++mt) {
      int ro = mt * 16 + r;
      int aoff = (ro * 64 + h4 * 16) ^ ((ro & 3) << 4);
      u16x8 pa = *reinterpret_cast<const u16x8*>(&As[buf][0] + aoff);
      #pragma unroll
      for (int nt = 0; nt < 4; ++nt) acc[mt][nt] = mfma16(pa, pbc[nt], acc[mt][nt]);
      if (w < 2) acch[mt] = mfma16(pa, pbhc, acch[mt]);
    }
    #pragma unroll
    for (int nt = 0; nt < 4; ++nt) pbc[nt] = pbn[nt];
    pbhc = pbhn;
    buf ^= 1;
  }
  #pragma unroll
  for (int mt = 0; mt < 4; ++mt)
    #pragma unroll
    for (int nt = 0; nt < 4; ++nt) {
      int c = w * 64 + nt * 16 + r;
      #pragma unroll
      for (int j = 0; j < 4; ++j) {
        int row = bm + mt * 16 + h4 * 4 + j;
        float v = acc[mt][nt][j] + bias[c];
        if (job == 0) out[(long)row * 512 + c] = v;
        else Vp[((row >> 3) * 256 + c) * 8 + (row & 7)] = f2bf(v);
      }
    }
  if (w < 2) {
    int c = w * 16 + r;
    float bb = b1[c];
    #pragma unroll
    for (int mt = 0; mt < 4; ++mt)
      #pragma unroll
      for (int j = 0; j < 4; ++j) {
        int row = bm + mt * 16 + h4 * 4 + j;
        H[row * DHID + c] = f2bf(tanhf(acch[mt][j] + bb));
      }
  }
}

// ---------------- K2: att = H @ W2 + b2, bf16 out ------------------------
__global__ __launch_bounds__(256) void k_att(
    const unsigned short* __restrict__ Hx, const unsigned short* __restrict__ Hn,
    const float* __restrict__ bx2, const float* __restrict__ bn2,
    const unsigned short* __restrict__ Wx2T, const unsigned short* __restrict__ Wn2T,
    unsigned short* __restrict__ xatt, unsigned short* __restrict__ natt) {
  const unsigned short* H; const float* b2; const unsigned short* WT; unsigned short* att;
  if (blockIdx.y == 0) { H = Hx; b2 = bx2; WT = Wx2T; att = xatt; }
  else                 { H = Hn; b2 = bn2; WT = Wn2T; att = natt; }
  int lane = threadIdx.x & 63, w = threadIdx.x >> 6;
  int r = lane & 15, h4 = lane >> 4;
  int row = blockIdx.x * 64 + w * 16 + r;
  u16x8 af = *reinterpret_cast<const u16x8*>(H + row * DHID + h4 * 8);
  u16x8 b0 = *reinterpret_cast<const u16x8*>(WT + r * DHID + h4 * 8);
  u16x8 b1 = *reinterpret_cast<const u16x8*>(WT + (16 + r) * DHID + h4 * 8);
  f32x4 z = {0.f, 0.f, 0.f, 0.f};
  f32x4 acc0 = mfma16(af, b0, z);
  f32x4 acc1 = mfma16(af, b1, z);
  int orow = blockIdx.x * 64 + w * 16 + h4 * 4;
  #pragma unroll
  for (int j = 0; j < 4; ++j) {
    att[(orow + j) * DHID + r]      = f2bf(acc0[j] + b2[r]);
    att[(orow + j) * DHID + 16 + r] = f2bf(acc1[j] + b2[16 + r]);
  }
}

// ---------------- K3: fused flash attention over neighbors ----------------
// Phase order per iter: QK -> mask/exp -> P-write -> __syncthreads ->
// {issue iter+2 adj/kf loads; PV with fresh ds_reads/Vp loads}.
// All global loads are issued immediately AFTER the barrier, so the next
// barrier's vmcnt(0) drain sees loads aged by a full iteration body
// (2-deep register pipeline; consumed two iters after issue, zero-wait).
__global__ __launch_bounds__(256, 4) void k_flash(
    const int* __restrict__ adj, const unsigned short* __restrict__ xatt,
    const unsigned short* __restrict__ natt, const unsigned short* __restrict__ Vp,
    float* __restrict__ out, unsigned short* __restrict__ accP,
    float* __restrict__ lP, int nc) {
  __shared__ unsigned short P[2][32 * 72];  // double-buffered 32x64 (+pad)
  __shared__ float lpart[4][32];
  int t = threadIdx.x;
  int lane = t & 63, w = t >> 6;
  int r = lane & 15, h4 = lane >> 4;
  int rb = blockIdx.x * 32;
  int L = NN / nc;
  int base = blockIdx.y * L;
  int NIT = L / 64;
  u16x8 qf0 = *reinterpret_cast<const u16x8*>(xatt + (rb + r) * DHID + h4 * 8);
  u16x8 qf1 = *reinterpret_cast<const u16x8*>(xatt + (rb + 16 + r) * DHID + h4 * 8);
  f32x4 o[2][4];
  #pragma unroll
  for (int i = 0; i < 2; ++i)
    #pragma unroll
    for (int j = 0; j < 4; ++j) o[i][j] = (f32x4){0.f, 0.f, 0.f, 0.f};
  float psum[8];
  #pragma unroll
  for (int i = 0; i < 8; ++i) psum[i] = 0.f;
  // 2-deep pipelines: A = iter i (ready), B = iter i+1 (in flight / ready)
  int adjA[8], adjB[8];
  u16x8 kfA, kfB;
  long arow = (long)rb * NN + w * 16 + r;  // lane's adj base (row rb, this col)
  #pragma unroll
  for (int rt = 0; rt < 2; ++rt)
    #pragma unroll
    for (int j = 0; j < 4; ++j) {
      long ro = (long)(rt * 16 + h4 * 4 + j) * NN;
      adjA[rt * 4 + j] = adj[arow + ro + base];
      adjB[rt * 4 + j] = adj[arow + ro + base + 64];
    }
  kfA = *reinterpret_cast<const u16x8*>(natt + (base + w * 16 + r) * DHID + h4 * 8);
  kfB = *reinterpret_cast<const u16x8*>(natt + (base + 64 + w * 16 + r) * DHID + h4 * 8);
  int buf = 0;
  int lastn = base + L - 64;
  for (int it = 0; it < NIT; ++it) {
    int n0 = base + it * 64;
    // ---- QK + mask/exp + P-write (uses A-slot registers, zero-wait) ----
    f32x4 z = {0.f, 0.f, 0.f, 0.f};
    f32x4 s0 = mfma16(qf0, kfA, z);
    f32x4 s1 = mfma16(qf1, kfA, z);
    unsigned short* Pb = &P[buf][0];
    #pragma unroll
    for (int rt = 0; rt < 2; ++rt) {
      f32x4 s = rt ? s1 : s0;
      #pragma unroll
      for (int j = 0; j < 4; ++j) {
        float sv = s[j];
        float lr = fminf(fmaxf(sv, 0.01f * sv), 60.f);  // leaky_relu + guard
        float p = (adjA[rt * 4 + j] > 0) ? __expf(lr) : 0.f;
        psum[rt * 4 + j] += p;
        Pb[(rt * 16 + h4 * 4 + j) * 72 + w * 16 + r] = f2bf(p);
      }
    }
    __syncthreads();  // P[buf] visible; drains (aged) in-flight loads
    // ---- post-barrier: rotate pipeline, issue loads for iter it+2 ----
    #pragma unroll
    for (int q = 0; q < 8; ++q) adjA[q] = adjB[q];
    kfA = kfB;
    int n2 = n0 + 128 <= lastn ? n0 + 128 : lastn;  // clamped (dup harmless)
    #pragma unroll
    for (int rt = 0; rt < 2; ++rt)
      #pragma unroll
      for (int j = 0; j < 4; ++j)
        adjB[rt * 4 + j] = adj[arow + (long)(rt * 16 + h4 * 4 + j) * NN + n2];
    kfB = *reinterpret_cast<const u16x8*>(natt + (n2 + w * 16 + r) * DHID + h4 * 8);
    // ---- PV phase: ds_reads + Vp loads then MFMA cluster ----
    u16x8 pa[2][2], vf[2][4];
    #pragma unroll
    for (int kb = 0; kb < 2; ++kb) {
      pa[kb][0] = *reinterpret_cast<const u16x8*>(Pb + r * 72 + kb * 32 + h4 * 8);
      pa[kb][1] = *reinterpret_cast<const u16x8*>(Pb + (16 + r) * 72 + kb * 32 + h4 * 8);
    }
    #pragma unroll
    for (int kb = 0; kb < 2; ++kb) {
      long vbase = ((long)((n0 + kb * 32) >> 3) + h4) * (DOUT * 8);
      #pragma unroll
      for (int nt = 0; nt < 4; ++nt)
        vf[kb][nt] = *reinterpret_cast<const u16x8*>(Vp + vbase + (w * 64 + nt * 16 + r) * 8);
    }
    #pragma unroll
    for (int kb = 0; kb < 2; ++kb)
      #pragma unroll
      for (int nt = 0; nt < 4; ++nt) {
        o[0][nt] = mfma16(pa[kb][0], vf[kb][nt], o[0][nt]);
        o[1][nt] = mfma16(pa[kb][1], vf[kb][nt], o[1][nt]);
      }
    buf ^= 1;  // old buf reads complete before its next overwrite (2 barriers away)
  }
  // row-sum: reduce psum over the 16 r-lanes (h4 groups independent)
  #pragma unroll
  for (int q = 1; q < 16; q <<= 1)
    #pragma unroll
    for (int i = 0; i < 8; ++i) psum[i] += __shfl_xor(psum[i], q);
  if (r == 0) {
    #pragma unroll
    for (int rt = 0; rt < 2; ++rt)
      #pragma unroll
      for (int j = 0; j < 4; ++j)
        lpart[w][rt * 16 + h4 * 4 + j] = psum[rt * 4 + j];
  }
  __syncthreads();
  if (nc == 1) {
    #pragma unroll
    for (int rt = 0; rt < 2; ++rt)
      #pragma unroll
      for (int nt = 0; nt < 4; ++nt) {
        int c = w * 64 + nt * 16 + r;
        #pragma unroll
        for (int j = 0; j < 4; ++j) {
          int rl = rt * 16 + h4 * 4 + j;
          float l = lpart[0][rl] + lpart[1][rl] + lpart[2][rl] + lpart[3][rl];
          out[(long)(rb + rl) * 512 + 256 + c] = o[rt][nt][j] / l;
        }
      }
  } else {
    long cb = (long)blockIdx.y * NX;
    #pragma unroll
    for (int rt = 0; rt < 2; ++rt)
      #pragma unroll
      for (int nt = 0; nt < 4; ++nt) {
        int c = w * 64 + nt * 16 + r;
        #pragma unroll
        for (int j = 0; j < 4; ++j) {
          int rl = rt * 16 + h4 * 4 + j;
          accP[(cb + rb + rl) * DOUT + c] = f2bf(o[rt][nt][j]);
        }
      }
    if (t < 32)
      lP[blockIdx.y * NX + rb + t] =
          lpart[0][t] + lpart[1][t] + lpart[2][t] + lpart[3][t];
  }
}

// ---------------- K4: combine neighbor-chunk partials ---------------------
__global__ __launch_bounds__(256) void k_combine(
    const unsigned short* __restrict__ accP, const float* __restrict__ lP,
    float* __restrict__ out, int nc) {
  long idx = (long)blockIdx.x * 256 + threadIdx.x;  // over NX*DOUT
  int row = (int)(idx >> 8), c = (int)(idx & 255);
  float s = 0.f, l = 0.f;
  for (int q = 0; q < nc; ++q) {
    s += bf2f(accP[(long)q * NX * DOUT + idx]);
    l += lP[q * NX + row];
  }
  out[(long)row * 512 + 256 + c] = s / l;
}

extern "C" void kernel_launch(void* const* d_in, const int* in_sizes, int n_in,
                              void* d_out, int out_size, void* d_ws, size_t ws_size,
                              hipStream_t stream) {
  const float* x    = (const float*)d_in[0];
  const float* neigh= (const float*)d_in[1];
  const int*   adj  = (const int*)d_in[2];
  const float* Wx1  = (const float*)d_in[3];
  const float* bx1  = (const float*)d_in[4];
  const float* Wx2  = (const float*)d_in[5];
  const float* bx2  = (const float*)d_in[6];
  const float* Wn1  = (const float*)d_in[7];
  const float* bn1  = (const float*)d_in[8];
  const float* Wn2  = (const float*)d_in[9];
  const float* bn2  = (const float*)d_in[10];
  const float* Wv   = (const float*)d_in[11];
  const float* bv   = (const float*)d_in[12];
  const float* Wfx  = (const float*)d_in[13];
  const float* bfx  = (const float*)d_in[14];
  float* out = (float*)d_out;
  char* ws = (char*)d_ws;

  unsigned short* xatt = (unsigned short*)(ws + 0);
  unsigned short* natt = (unsigned short*)(ws + 524288);
  unsigned short* Hx   = (unsigned short*)(ws + 1048576);
  unsigned short* Hn   = (unsigned short*)(ws + 1572864);
  unsigned short* Vp   = (unsigned short*)(ws + 2097152);
  unsigned short* WvT  = (unsigned short*)(ws + 6291456);
  unsigned short* WfxT = (unsigned short*)(ws + 6553600);
  unsigned short* Wx1T = (unsigned short*)(ws + 6815744);
  unsigned short* Wn1T = (unsigned short*)(ws + 6848512);
  unsigned short* Wx2T = (unsigned short*)(ws + 6881280);
  unsigned short* Wn2T = (unsigned short*)(ws + 6883328);

  const size_t OFF_ACC = 7340032;                   // 7 MB
  const size_t CHUNK_ACC = (size_t)NX * DOUT * 2;   // 4 MB bf16 per chunk
  size_t need4 = OFF_ACC + 4 * (CHUNK_ACC + (size_t)NX * 4);
  size_t need2 = OFF_ACC + 2 * (CHUNK_ACC + (size_t)NX * 4);
  int nc = (ws_size >= need4) ? 4 : (ws_size >= need2) ? 2 : 1;
  unsigned short* accP = (unsigned short*)(ws + OFF_ACC);
  float* lP = (float*)(ws + OFF_ACC + (size_t)nc * CHUNK_ACC);

  k_wt<<<dim3(128, 6), 256, 0, stream>>>(Wv, Wfx, Wx1, Wn1, Wx2, Wn2,
                                         WvT, WfxT, Wx1T, Wn1T, Wx2T, Wn2T);
  k_prep<<<dim3(128, 2), 256, 0, stream>>>(x, neigh, bfx, bv, bx1, bn1,
                                           WfxT, WvT, Wx1T, Wn1T, out, Vp, Hx, Hn);
  k_att<<<dim3(128, 2), 256, 0, stream>>>(Hx, Hn, bx2, bn2, Wx2T, Wn2T, xatt, natt);
  k_flash<<<dim3(256, nc), 256, 0, stream>>>(adj, xatt, natt, Vp, out, accP, lP, nc);
  if (nc > 1)
    k_combine<<<dim3(NX * DOUT / 256), 256, 0, stream>>>(accP, lP, out, nc);
}

// Round 5
// 487.695 us; speedup vs baseline: 1.1604x; 1.0187x over previous
//
#include <hip/hip_runtime.h>
#include <hip/hip_bf16.h>

#define NX 8192
#define NN 8192
#define DIN 512
#define DHID 32
#define DOUT 256

typedef __bf16 bf16x8 __attribute__((ext_vector_type(8)));
typedef float f32x4 __attribute__((ext_vector_type(4)));
typedef unsigned short u16x8 __attribute__((ext_vector_type(8)));

__device__ __forceinline__ unsigned short f2bf(float f) {
  __hip_bfloat16 h = __float2bfloat16(f);
  return __builtin_bit_cast(unsigned short, h);
}
__device__ __forceinline__ float bf2f(unsigned short u) {
  unsigned int v = ((unsigned int)u) << 16;
  return __builtin_bit_cast(float, v);
}
__device__ __forceinline__ f32x4 mfma16(u16x8 a, u16x8 b, f32x4 c) {
  return __builtin_amdgcn_mfma_f32_16x16x32_bf16(
      __builtin_bit_cast(bf16x8, a), __builtin_bit_cast(bf16x8, b), c, 0, 0, 0);
}
__device__ __forceinline__ u16x8 cvt8(float4 a0, float4 a1) {
  u16x8 u;
  u[0] = f2bf(a0.x); u[1] = f2bf(a0.y); u[2] = f2bf(a0.z); u[3] = f2bf(a0.w);
  u[4] = f2bf(a1.x); u[5] = f2bf(a1.y); u[6] = f2bf(a1.z); u[7] = f2bf(a1.w);
  return u;
}

// ---------------- K0: LDS-tiled transpose + bf16 convert ------------------
__global__ __launch_bounds__(256) void k_wt(
    const float* __restrict__ Wv, const float* __restrict__ Wfx,
    const float* __restrict__ Wx1, const float* __restrict__ Wn1,
    const float* __restrict__ Wx2, const float* __restrict__ Wn2,
    unsigned short* __restrict__ WvT, unsigned short* __restrict__ WfxT,
    unsigned short* __restrict__ Wx1T, unsigned short* __restrict__ Wn1T,
    unsigned short* __restrict__ Wx2T, unsigned short* __restrict__ Wn2T) {
  const float* src; unsigned short* dst; int K, C;
  switch (blockIdx.y) {
    case 0:  src = Wv;  dst = WvT;  K = DIN; C = 256; break;
    case 1:  src = Wfx; dst = WfxT; K = DIN; C = 256; break;
    case 2:  src = Wx1; dst = Wx1T; K = DIN; C = 32;  break;
    case 3:  src = Wn1; dst = Wn1T; K = DIN; C = 32;  break;
    case 4:  src = Wx2; dst = Wx2T; K = 32;  C = 32;  break;
    default: src = Wn2; dst = Wn2T; K = 32;  C = 32;  break;
  }
  int tc = C >> 5, tk = K >> 5;
  if ((int)blockIdx.x >= tc * tk) return;
  int ik = blockIdx.x / tc, ic = blockIdx.x % tc;
  __shared__ float tile[32][33];
  int t = threadIdx.x, tx = t & 31, ty0 = t >> 5;
  #pragma unroll
  for (int q = 0; q < 4; ++q) {
    int ty = ty0 + q * 8;
    tile[ty][tx] = src[(ik * 32 + ty) * C + ic * 32 + tx];
  }
  __syncthreads();
  #pragma unroll
  for (int q = 0; q < 4; ++q) {
    int ty = ty0 + q * 8;
    dst[(ic * 32 + ty) * K + ik * 32 + tx] = f2bf(tile[tx][ty]);
  }
}

// ------- K1: merged prep GEMM: A@{Wfx|Wv} (N=256) and tanh(A@W1) (N=32) ----
__global__ __launch_bounds__(256) void k_prep(
    const float* __restrict__ x, const float* __restrict__ neigh,
    const float* __restrict__ bfx, const float* __restrict__ bv,
    const float* __restrict__ bx1, const float* __restrict__ bn1,
    const unsigned short* __restrict__ WfxT, const unsigned short* __restrict__ WvT,
    const unsigned short* __restrict__ Wx1T, const unsigned short* __restrict__ Wn1T,
    float* __restrict__ out, unsigned short* __restrict__ Vp,
    unsigned short* __restrict__ Hx, unsigned short* __restrict__ Hn) {
  int job = blockIdx.y;
  const float* A = job ? neigh : x;
  const float* bias = job ? bv : bfx;
  const float* b1 = job ? bn1 : bx1;
  const unsigned short* WT = job ? WvT : WfxT;
  const unsigned short* W1T = job ? Wn1T : Wx1T;
  unsigned short* H = job ? Hn : Hx;
  __shared__ __align__(16) char As[2][64 * 64];
  int t = threadIdx.x;
  int lane = t & 63, w = t >> 6;
  int r = lane & 15, h4 = lane >> 4;
  int bm = blockIdx.x * 64;
  f32x4 acc[4][4];
  f32x4 acch[4];
  #pragma unroll
  for (int i = 0; i < 4; ++i) {
    acch[i] = (f32x4){0.f, 0.f, 0.f, 0.f};
    #pragma unroll
    for (int j = 0; j < 4; ++j) acc[i][j] = (f32x4){0.f, 0.f, 0.f, 0.f};
  }
  int srow = t >> 2, kq = t & 3;
  const float* ap = A + (long)(bm + srow) * DIN + kq * 8;
  float4 a0 = *reinterpret_cast<const float4*>(ap);
  float4 a1 = *reinterpret_cast<const float4*>(ap + 4);
  u16x8 pbc[4], pbhc;
  #pragma unroll
  for (int nt = 0; nt < 4; ++nt)
    pbc[nt] = *reinterpret_cast<const u16x8*>(WT + (w * 64 + nt * 16 + r) * DIN + h4 * 8);
  if (w < 2)
    pbhc = *reinterpret_cast<const u16x8*>(W1T + (w * 16 + r) * DIN + h4 * 8);
  int boff = (srow * 64 + kq * 16) ^ ((srow & 3) << 4);
  int buf = 0;
  for (int kk = 0; kk < 16; ++kk) {
    u16x8 u = cvt8(a0, a1);
    *reinterpret_cast<u16x8*>(&As[buf][0] + boff) = u;
    __syncthreads();
    u16x8 pbn[4], pbhn;
    if (kk < 15) {
      a0 = *reinterpret_cast<const float4*>(ap + (kk + 1) * 32);
      a1 = *reinterpret_cast<const float4*>(ap + (kk + 1) * 32 + 4);
      #pragma unroll
      for (int nt = 0; nt < 4; ++nt)
        pbn[nt] = *reinterpret_cast<const u16x8*>(
            WT + (w * 64 + nt * 16 + r) * DIN + (kk + 1) * 32 + h4 * 8);
      if (w < 2)
        pbhn = *reinterpret_cast<const u16x8*>(
            W1T + (w * 16 + r) * DIN + (kk + 1) * 32 + h4 * 8);
    }
    #pragma unroll
    for (int mt = 0; mt < 4; ++mt) {
      int ro = mt * 16 + r;
      int aoff = (ro * 64 + h4 * 16) ^ ((ro & 3) << 4);
      u16x8 pa = *reinterpret_cast<const u16x8*>(&As[buf][0] + aoff);
      #pragma unroll
      for (int nt = 0; nt < 4; ++nt) acc[mt][nt] = mfma16(pa, pbc[nt], acc[mt][nt]);
      if (w < 2) acch[mt] = mfma16(pa, pbhc, acch[mt]);
    }
    #pragma unroll
    for (int nt = 0; nt < 4; ++nt) pbc[nt] = pbn[nt];
    pbhc = pbhn;
    buf ^= 1;
  }
  #pragma unroll
  for (int mt = 0; mt < 4; ++mt)
    #pragma unroll
    for (int nt = 0; nt < 4; ++nt) {
      int c = w * 64 + nt * 16 + r;
      #pragma unroll
      for (int j = 0; j < 4; ++j) {
        int row = bm + mt * 16 + h4 * 4 + j;
        float v = acc[mt][nt][j] + bias[c];
        if (job == 0) out[(long)row * 512 + c] = v;
        else Vp[((row >> 3) * 256 + c) * 8 + (row & 7)] = f2bf(v);
      }
    }
  if (w < 2) {
    int c = w * 16 + r;
    float bb = b1[c];
    #pragma unroll
    for (int mt = 0; mt < 4; ++mt)
      #pragma unroll
      for (int j = 0; j < 4; ++j) {
        int row = bm + mt * 16 + h4 * 4 + j;
        H[row * DHID + c] = f2bf(tanhf(acch[mt][j] + bb));
      }
  }
}

// ---------------- K2: att = H @ W2 + b2, bf16 out ------------------------
__global__ __launch_bounds__(256) void k_att(
    const unsigned short* __restrict__ Hx, const unsigned short* __restrict__ Hn,
    const float* __restrict__ bx2, const float* __restrict__ bn2,
    const unsigned short* __restrict__ Wx2T, const unsigned short* __restrict__ Wn2T,
    unsigned short* __restrict__ xatt, unsigned short* __restrict__ natt) {
  const unsigned short* H; const float* b2; const unsigned short* WT; unsigned short* att;
  if (blockIdx.y == 0) { H = Hx; b2 = bx2; WT = Wx2T; att = xatt; }
  else                 { H = Hn; b2 = bn2; WT = Wn2T; att = natt; }
  int lane = threadIdx.x & 63, w = threadIdx.x >> 6;
  int r = lane & 15, h4 = lane >> 4;
  int row = blockIdx.x * 64 + w * 16 + r;
  u16x8 af = *reinterpret_cast<const u16x8*>(H + row * DHID + h4 * 8);
  u16x8 b0 = *reinterpret_cast<const u16x8*>(WT + r * DHID + h4 * 8);
  u16x8 b1 = *reinterpret_cast<const u16x8*>(WT + (16 + r) * DHID + h4 * 8);
  f32x4 z = {0.f, 0.f, 0.f, 0.f};
  f32x4 acc0 = mfma16(af, b0, z);
  f32x4 acc1 = mfma16(af, b1, z);
  int orow = blockIdx.x * 64 + w * 16 + h4 * 4;
  #pragma unroll
  for (int j = 0; j < 4; ++j) {
    att[(orow + j) * DHID + r]      = f2bf(acc0[j] + b2[r]);
    att[(orow + j) * DHID + 16 + r] = f2bf(acc1[j] + b2[16 + r]);
  }
}

// ---------------- K3: fused flash attention over neighbors ----------------
// R4 structure (verified). R5 change: adj loads are NON-TEMPORAL (`nt` /
// evict-first) so the 268 MB adj stream stops thrashing the per-XCD L2s.
// Vp (4 MB) then stays L2-resident: PV's value reads are served from L2
// instead of hammering the Infinity Cache (the R4 bottleneck: ~1.07 GB of
// Vp traffic -> ~7 TB/s L3 demand).
__global__ __launch_bounds__(256, 4) void k_flash(
    const int* __restrict__ adj, const unsigned short* __restrict__ xatt,
    const unsigned short* __restrict__ natt, const unsigned short* __restrict__ Vp,
    float* __restrict__ out, unsigned short* __restrict__ accP,
    float* __restrict__ lP, int nc) {
  __shared__ unsigned short P[2][32 * 72];  // double-buffered 32x64 (+pad)
  __shared__ float lpart[4][32];
  int t = threadIdx.x;
  int lane = t & 63, w = t >> 6;
  int r = lane & 15, h4 = lane >> 4;
  int rb = blockIdx.x * 32;
  int L = NN / nc;
  int base = blockIdx.y * L;
  int NIT = L / 64;
  u16x8 qf0 = *reinterpret_cast<const u16x8*>(xatt + (rb + r) * DHID + h4 * 8);
  u16x8 qf1 = *reinterpret_cast<const u16x8*>(xatt + (rb + 16 + r) * DHID + h4 * 8);
  f32x4 o[2][4];
  #pragma unroll
  for (int i = 0; i < 2; ++i)
    #pragma unroll
    for (int j = 0; j < 4; ++j) o[i][j] = (f32x4){0.f, 0.f, 0.f, 0.f};
  float psum[8];
  #pragma unroll
  for (int i = 0; i < 8; ++i) psum[i] = 0.f;
  // 2-deep pipelines: A = iter i (ready), B = iter i+1 (in flight / ready)
  int adjA[8], adjB[8];
  u16x8 kfA, kfB;
  long arow = (long)rb * NN + w * 16 + r;  // lane's adj base (row rb, this col)
  #pragma unroll
  for (int rt = 0; rt < 2; ++rt)
    #pragma unroll
    for (int j = 0; j < 4; ++j) {
      long ro = (long)(rt * 16 + h4 * 4 + j) * NN;
      adjA[rt * 4 + j] = __builtin_nontemporal_load(&adj[arow + ro + base]);
      adjB[rt * 4 + j] = __builtin_nontemporal_load(&adj[arow + ro + base + 64]);
    }
  kfA = *reinterpret_cast<const u16x8*>(natt + (base + w * 16 + r) * DHID + h4 * 8);
  kfB = *reinterpret_cast<const u16x8*>(natt + (base + 64 + w * 16 + r) * DHID + h4 * 8);
  int buf = 0;
  int lastn = base + L - 64;
  for (int it = 0; it < NIT; ++it) {
    int n0 = base + it * 64;
    // ---- QK + mask/exp + P-write (uses A-slot registers, zero-wait) ----
    f32x4 z = {0.f, 0.f, 0.f, 0.f};
    f32x4 s0 = mfma16(qf0, kfA, z);
    f32x4 s1 = mfma16(qf1, kfA, z);
    unsigned short* Pb = &P[buf][0];
    #pragma unroll
    for (int rt = 0; rt < 2; ++rt) {
      f32x4 s = rt ? s1 : s0;
      #pragma unroll
      for (int j = 0; j < 4; ++j) {
        float sv = s[j];
        float lr = fminf(fmaxf(sv, 0.01f * sv), 60.f);  // leaky_relu + guard
        float p = (adjA[rt * 4 + j] > 0) ? __expf(lr) : 0.f;
        psum[rt * 4 + j] += p;
        Pb[(rt * 16 + h4 * 4 + j) * 72 + w * 16 + r] = f2bf(p);
      }
    }
    __syncthreads();  // P[buf] visible; drains (aged) in-flight loads
    // ---- post-barrier: rotate pipeline, issue loads for iter it+2 ----
    #pragma unroll
    for (int q = 0; q < 8; ++q) adjA[q] = adjB[q];
    kfA = kfB;
    int n2 = n0 + 128 <= lastn ? n0 + 128 : lastn;  // clamped (dup harmless)
    #pragma unroll
    for (int rt = 0; rt < 2; ++rt)
      #pragma unroll
      for (int j = 0; j < 4; ++j)
        adjB[rt * 4 + j] = __builtin_nontemporal_load(
            &adj[arow + (long)(rt * 16 + h4 * 4 + j) * NN + n2]);
    kfB = *reinterpret_cast<const u16x8*>(natt + (n2 + w * 16 + r) * DHID + h4 * 8);
    // ---- PV phase: ds_reads + Vp loads then MFMA cluster ----
    u16x8 pa[2][2], vf[2][4];
    #pragma unroll
    for (int kb = 0; kb < 2; ++kb) {
      pa[kb][0] = *reinterpret_cast<const u16x8*>(Pb + r * 72 + kb * 32 + h4 * 8);
      pa[kb][1] = *reinterpret_cast<const u16x8*>(Pb + (16 + r) * 72 + kb * 32 + h4 * 8);
    }
    #pragma unroll
    for (int kb = 0; kb < 2; ++kb) {
      long vbase = ((long)((n0 + kb * 32) >> 3) + h4) * (DOUT * 8);
      #pragma unroll
      for (int nt = 0; nt < 4; ++nt)
        vf[kb][nt] = *reinterpret_cast<const u16x8*>(Vp + vbase + (w * 64 + nt * 16 + r) * 8);
    }
    #pragma unroll
    for (int kb = 0; kb < 2; ++kb)
      #pragma unroll
      for (int nt = 0; nt < 4; ++nt) {
        o[0][nt] = mfma16(pa[kb][0], vf[kb][nt], o[0][nt]);
        o[1][nt] = mfma16(pa[kb][1], vf[kb][nt], o[1][nt]);
      }
    buf ^= 1;  // old buf reads complete before its next overwrite (2 barriers away)
  }
  // row-sum: reduce psum over the 16 r-lanes (h4 groups independent)
  #pragma unroll
  for (int q = 1; q < 16; q <<= 1)
    #pragma unroll
    for (int i = 0; i < 8; ++i) psum[i] += __shfl_xor(psum[i], q);
  if (r == 0) {
    #pragma unroll
    for (int rt = 0; rt < 2; ++rt)
      #pragma unroll
      for (int j = 0; j < 4; ++j)
        lpart[w][rt * 16 + h4 * 4 + j] = psum[rt * 4 + j];
  }
  __syncthreads();
  if (nc == 1) {
    #pragma unroll
    for (int rt = 0; rt < 2; ++rt)
      #pragma unroll
      for (int nt = 0; nt < 4; ++nt) {
        int c = w * 64 + nt * 16 + r;
        #pragma unroll
        for (int j = 0; j < 4; ++j) {
          int rl = rt * 16 + h4 * 4 + j;
          float l = lpart[0][rl] + lpart[1][rl] + lpart[2][rl] + lpart[3][rl];
          out[(long)(rb + rl) * 512 + 256 + c] = o[rt][nt][j] / l;
        }
      }
  } else {
    long cb = (long)blockIdx.y * NX;
    #pragma unroll
    for (int rt = 0; rt < 2; ++rt)
      #pragma unroll
      for (int nt = 0; nt < 4; ++nt) {
        int c = w * 64 + nt * 16 + r;
        #pragma unroll
        for (int j = 0; j < 4; ++j) {
          int rl = rt * 16 + h4 * 4 + j;
          accP[(cb + rb + rl) * DOUT + c] = f2bf(o[rt][nt][j]);
        }
      }
    if (t < 32)
      lP[blockIdx.y * NX + rb + t] =
          lpart[0][t] + lpart[1][t] + lpart[2][t] + lpart[3][t];
  }
}

// ---------------- K4: combine neighbor-chunk partials ---------------------
__global__ __launch_bounds__(256) void k_combine(
    const unsigned short* __restrict__ accP, const float* __restrict__ lP,
    float* __restrict__ out, int nc) {
  long idx = (long)blockIdx.x * 256 + threadIdx.x;  // over NX*DOUT
  int row = (int)(idx >> 8), c = (int)(idx & 255);
  float s = 0.f, l = 0.f;
  for (int q = 0; q < nc; ++q) {
    s += bf2f(accP[(long)q * NX * DOUT + idx]);
    l += lP[q * NX + row];
  }
  out[(long)row * 512 + 256 + c] = s / l;
}

extern "C" void kernel_launch(void* const* d_in, const int* in_sizes, int n_in,
                              void* d_out, int out_size, void* d_ws, size_t ws_size,
                              hipStream_t stream) {
  const float* x    = (const float*)d_in[0];
  const float* neigh= (const float*)d_in[1];
  const int*   adj  = (const int*)d_in[2];
  const float* Wx1  = (const float*)d_in[3];
  const float* bx1  = (const float*)d_in[4];
  const float* Wx2  = (const float*)d_in[5];
  const float* bx2  = (const float*)d_in[6];
  const float* Wn1  = (const float*)d_in[7];
  const float* bn1  = (const float*)d_in[8];
  const float* Wn2  = (const float*)d_in[9];
  const float* bn2  = (const float*)d_in[10];
  const float* Wv   = (const float*)d_in[11];
  const float* bv   = (const float*)d_in[12];
  const float* Wfx  = (const float*)d_in[13];
  const float* bfx  = (const float*)d_in[14];
  float* out = (float*)d_out;
  char* ws = (char*)d_ws;

  unsigned short* xatt = (unsigned short*)(ws + 0);
  unsigned short* natt = (unsigned short*)(ws + 524288);
  unsigned short* Hx   = (unsigned short*)(ws + 1048576);
  unsigned short* Hn   = (unsigned short*)(ws + 1572864);
  unsigned short* Vp   = (unsigned short*)(ws + 2097152);
  unsigned short* WvT  = (unsigned short*)(ws + 6291456);
  unsigned short* WfxT = (unsigned short*)(ws + 6553600);
  unsigned short* Wx1T = (unsigned short*)(ws + 6815744);
  unsigned short* Wn1T = (unsigned short*)(ws + 6848512);
  unsigned short* Wx2T = (unsigned short*)(ws + 6881280);
  unsigned short* Wn2T = (unsigned short*)(ws + 6883328);

  const size_t OFF_ACC = 7340032;                   // 7 MB
  const size_t CHUNK_ACC = (size_t)NX * DOUT * 2;   // 4 MB bf16 per chunk
  size_t need4 = OFF_ACC + 4 * (CHUNK_ACC + (size_t)NX * 4);
  size_t need2 = OFF_ACC + 2 * (CHUNK_ACC + (size_t)NX * 4);
  int nc = (ws_size >= need4) ? 4 : (ws_size >= need2) ? 2 : 1;
  unsigned short* accP = (unsigned short*)(ws + OFF_ACC);
  float* lP = (float*)(ws + OFF_ACC + (size_t)nc * CHUNK_ACC);

  k_wt<<<dim3(128, 6), 256, 0, stream>>>(Wv, Wfx, Wx1, Wn1, Wx2, Wn2,
                                         WvT, WfxT, Wx1T, Wn1T, Wx2T, Wn2T);
  k_prep<<<dim3(128, 2), 256, 0, stream>>>(x, neigh, bfx, bv, bx1, bn1,
                                           WfxT, WvT, Wx1T, Wn1T, out, Vp, Hx, Hn);
  k_att<<<dim3(128, 2), 256, 0, stream>>>(Hx, Hn, bx2, bn2, Wx2T, Wn2T, xatt, natt);
  k_flash<<<dim3(256, nc), 256, 0, stream>>>(adj, xatt, natt, Vp, out, accP, lP, nc);
  if (nc > 1)
    k_combine<<<dim3(NX * DOUT / 256), 256, 0, stream>>>(accP, lP, out, nc);
}